// Round 1
// baseline (53.661 us; speedup 1.0000x reference)
//
#include <hip/hip_runtime.h>

typedef unsigned long long u64;

// Exact integer re-implementation of the reference "spiking" fp64-multiplier
// circuit. Bit convention: array index j (0..63) of a row == bit (63-j) of
// the packed uint64 (sign at array[0] == bit 63).
__device__ __forceinline__ u64 fp64mul_circuit(u64 a, u64 b) {
    const u64 FRACM = 0xFFFFFFFFFFFFFULL; // low 52 bits
    u64 sA = a >> 63, sB = b >> 63;
    unsigned eA = (unsigned)((a >> 52) & 0x7FF);
    unsigned eB = (unsigned)((b >> 52) & 0x7FF);
    u64 mA = a & FRACM, mB = b & FRACM;
    u64 sign = sA ^ sB;

    // 54-bit significands (implicit bit = exponent nonzero; circuit uses
    // biased exp as-is for subnormals — replicate, don't "fix").
    u64 MA = mA | ((u64)(eA != 0) << 52);
    u64 MB = mB | ((u64)(eB != 0) << 52);
    __uint128_t P = (__uint128_t)MA * (__uint128_t)MB; // < 2^106, held in 108-bit field

    // Leading-zero count within the 108-bit field (circuit returns 108 if P==0).
    u64 hi = (u64)(P >> 64), lo = (u64)P;
    int lzc;
    if (hi)      lzc = __clzll(hi) - 20;      // bits 107..64 live in hi[43:0]
    else if (lo) lzc = 44 + __clzll(lo);
    else         lzc = 108;

    // Barrel left-shift: leading one -> bit 107.
    __uint128_t norm = P << lzc; // lzc<=108<128, P==0 case yields 0

    u64 mant53     = (u64)(norm >> 55);                  // bits 107..55
    unsigned guard = (unsigned)(((u64)(norm >> 54)) & 1);
    unsigned lsb   = (unsigned)(mant53 & 1);
    unsigned sticky = ((norm & ((((__uint128_t)1) << 54) - 1)) != 0) ? 1u : 0u;
    unsigned rnd   = guard & (sticky | lsb);             // round to nearest even

    u64 sum = mant53 + (u64)rnd;                         // 53-bit add + carry out
    unsigned rcarry = (unsigned)((sum >> 53) & 1);
    u64 frac52 = sum & FRACM;

    // 13-bit two's-complement exponent chain, exactly as the ripple adders do.
    int Emod = ((int)eA + (int)eB + 3 - 1023 - lzc + (int)rcarry) & 8191;
    int neg    = (Emod >> 12) & 1;
    int e_zero = (Emod == 0) ? 1 : 0;
    int underflow = neg | e_zero;
    int overflow  = (neg ^ 1) & ((((Emod >> 11) & 1) | ((Emod & 0x7FF) == 0x7FF)) ? 1 : 0);
    u64 exp11 = (u64)(Emod & 0x7FF);

    // Special-case flags.
    bool a_ones = (eA == 0x7FF), b_ones = (eB == 0x7FF);
    bool a_mnz = (mA != 0), b_mnz = (mB != 0);
    bool A_nan = a_ones && a_mnz,  B_nan = b_ones && b_mnz;
    bool A_inf = a_ones && !a_mnz, B_inf = b_ones && !b_mnz;
    bool A_zero = (eA == 0) && !a_mnz, B_zero = (eB == 0) && !b_mnz;

    bool nan_sel  = A_nan || B_nan || (A_inf && B_zero) || (B_inf && A_zero);
    bool inf_sel  = A_inf || B_inf || (overflow != 0);
    bool zero_sel = A_zero || B_zero || (underflow != 0);

    // Mux order: zero, then inf, then nan (later overrides earlier).
    u64 expo = exp11, fraco = frac52;
    if (zero_sel) { expo = 0;     fraco = 0; }
    if (inf_sel)  { expo = 0x7FF; fraco = 0; }
    if (nan_sel)  { expo = 0x7FF; fraco = 1ULL << 51; } // qnan: frac MSB only

    return (sign << 63) | (expo << 52) | fraco;
}

__global__ __launch_bounds__(256) void spike_fp64_mul_kernel(
    const float* __restrict__ A, const float* __restrict__ B,
    float* __restrict__ out, int n)
{
    int row = blockIdx.x * blockDim.x + threadIdx.x;
    if (row >= n) return;

    const float4* a4 = reinterpret_cast<const float4*>(A + (size_t)row * 64);
    const float4* b4 = reinterpret_cast<const float4*>(B + (size_t)row * 64);

    u64 a = 0, b = 0;
    #pragma unroll
    for (int j = 0; j < 16; ++j) {
        float4 va = a4[j];
        float4 vb = b4[j];
        int s = 63 - j * 4;
        a |= ((u64)(va.x > 0.5f)) << s;
        a |= ((u64)(va.y > 0.5f)) << (s - 1);
        a |= ((u64)(va.z > 0.5f)) << (s - 2);
        a |= ((u64)(va.w > 0.5f)) << (s - 3);
        b |= ((u64)(vb.x > 0.5f)) << s;
        b |= ((u64)(vb.y > 0.5f)) << (s - 1);
        b |= ((u64)(vb.z > 0.5f)) << (s - 2);
        b |= ((u64)(vb.w > 0.5f)) << (s - 3);
    }

    u64 r = fp64mul_circuit(a, b);

    float4* o4 = reinterpret_cast<float4*>(out + (size_t)row * 64);
    #pragma unroll
    for (int j = 0; j < 16; ++j) {
        int s = 63 - j * 4;
        float4 v;
        v.x = (float)((r >> s) & 1);
        v.y = (float)((r >> (s - 1)) & 1);
        v.z = (float)((r >> (s - 2)) & 1);
        v.w = (float)((r >> (s - 3)) & 1);
        o4[j] = v;
    }
}

extern "C" void kernel_launch(void* const* d_in, const int* in_sizes, int n_in,
                              void* d_out, int out_size, void* d_ws, size_t ws_size,
                              hipStream_t stream) {
    const float* A = (const float*)d_in[0];
    const float* B = (const float*)d_in[1];
    float* out = (float*)d_out;
    int n = in_sizes[0] / 64; // rows
    int block = 256;
    int grid = (n + block - 1) / block;
    spike_fp64_mul_kernel<<<grid, block, 0, stream>>>(A, B, out, n);
}

// Round 2
// 24.113 us; speedup vs baseline: 2.2254x; 2.2254x over previous
//
#include <hip/hip_runtime.h>

typedef unsigned long long u64;

// Exact integer re-implementation of the reference "spiking" fp64-multiplier
// circuit. Bit convention: array index j (0..63) of a row == bit (63-j) of
// the packed uint64 (sign at array[0] == bit 63).
__device__ __forceinline__ u64 fp64mul_circuit(u64 a, u64 b) {
    const u64 FRACM = 0xFFFFFFFFFFFFFULL; // low 52 bits
    u64 sA = a >> 63, sB = b >> 63;
    unsigned eA = (unsigned)((a >> 52) & 0x7FF);
    unsigned eB = (unsigned)((b >> 52) & 0x7FF);
    u64 mA = a & FRACM, mB = b & FRACM;
    u64 sign = sA ^ sB;

    // 54-bit significands (implicit bit = exponent nonzero; circuit uses
    // biased exp as-is for subnormals — replicate, don't "fix").
    u64 MA = mA | ((u64)(eA != 0) << 52);
    u64 MB = mB | ((u64)(eB != 0) << 52);
    __uint128_t P = (__uint128_t)MA * (__uint128_t)MB; // < 2^106, in 108-bit field

    // Leading-zero count within the 108-bit field (circuit returns 108 if P==0).
    u64 hi = (u64)(P >> 64), lo = (u64)P;
    int lzc;
    if (hi)      lzc = __clzll(hi) - 20;      // bits 107..64 live in hi[43:0]
    else if (lo) lzc = 44 + __clzll(lo);
    else         lzc = 108;

    // Barrel left-shift: leading one -> bit 107.
    __uint128_t norm = P << lzc; // lzc<=108<128, P==0 case yields 0

    u64 mant53     = (u64)(norm >> 55);                  // bits 107..55
    unsigned guard = (unsigned)(((u64)(norm >> 54)) & 1);
    unsigned lsb   = (unsigned)(mant53 & 1);
    unsigned sticky = ((norm & ((((__uint128_t)1) << 54) - 1)) != 0) ? 1u : 0u;
    unsigned rnd   = guard & (sticky | lsb);             // round to nearest even

    u64 sum = mant53 + (u64)rnd;                         // 53-bit add + carry out
    unsigned rcarry = (unsigned)((sum >> 53) & 1);
    u64 frac52 = sum & FRACM;

    // 13-bit two's-complement exponent chain, exactly as the ripple adders do.
    int Emod = ((int)eA + (int)eB + 3 - 1023 - lzc + (int)rcarry) & 8191;
    int neg    = (Emod >> 12) & 1;
    int e_zero = (Emod == 0) ? 1 : 0;
    int underflow = neg | e_zero;
    int overflow  = (neg ^ 1) & ((((Emod >> 11) & 1) | ((Emod & 0x7FF) == 0x7FF)) ? 1 : 0);
    u64 exp11 = (u64)(Emod & 0x7FF);

    // Special-case flags.
    bool a_ones = (eA == 0x7FF), b_ones = (eB == 0x7FF);
    bool a_mnz = (mA != 0), b_mnz = (mB != 0);
    bool A_nan = a_ones && a_mnz,  B_nan = b_ones && b_mnz;
    bool A_inf = a_ones && !a_mnz, B_inf = b_ones && !b_mnz;
    bool A_zero = (eA == 0) && !a_mnz, B_zero = (eB == 0) && !b_mnz;

    bool nan_sel  = A_nan || B_nan || (A_inf && B_zero) || (B_inf && A_zero);
    bool inf_sel  = A_inf || B_inf || (overflow != 0);
    bool zero_sel = A_zero || B_zero || (underflow != 0);

    // Mux order: zero, then inf, then nan (later overrides earlier).
    u64 expo = exp11, fraco = frac52;
    if (zero_sel) { expo = 0;     fraco = 0; }
    if (inf_sel)  { expo = 0x7FF; fraco = 0; }
    if (nan_sel)  { expo = 0x7FF; fraco = 1ULL << 51; } // qnan: frac MSB only

    return (sign << 63) | (expo << 52) | fraco;
}

// One wave = 64 rows. Lane l handles bit-column l for loads/stores
// (fully coalesced: 64 lanes x 4B = 256B contiguous per instruction).
// float->bit packing is a single __ballot per row; lane r keeps row r.
__global__ __launch_bounds__(256) void spike_fp64_mul_kernel(
    const float* __restrict__ A, const float* __restrict__ B,
    float* __restrict__ out, int n)
{
    int gtid = blockIdx.x * blockDim.x + threadIdx.x;
    int wave = gtid >> 6;
    int lane = threadIdx.x & 63;
    int nwaves = n >> 6;
    if (wave >= nwaves) return;

    size_t rowbase = (size_t)wave << 6;               // first row of this wave
    const float* pa = A + rowbase * 64 + lane;
    const float* pb = B + rowbase * 64 + lane;

    u64 a = 0, b = 0;
    #pragma unroll
    for (int r = 0; r < 64; ++r) {
        float va = pa[(size_t)r * 64];
        float vb = pb[(size_t)r * 64];
        u64 balA = __ballot(va > 0.5f);               // bit l = array index l of row r
        u64 balB = __ballot(vb > 0.5f);
        if (lane == r) { a = balA; b = balB; }        // route row r to lane r
    }

    // ballot order: bit l = array idx l; circuit wants bit 63-j for idx j.
    u64 res = fp64mul_circuit(__brevll(a), __brevll(b));

    float* po = out + rowbase * 64 + lane;
    #pragma unroll
    for (int r = 0; r < 64; ++r) {
        u64 v = __shfl(res, r);                       // row base+r's result -> all lanes
        po[(size_t)r * 64] = (float)((v >> (63 - lane)) & 1);
    }
}

extern "C" void kernel_launch(void* const* d_in, const int* in_sizes, int n_in,
                              void* d_out, int out_size, void* d_ws, size_t ws_size,
                              hipStream_t stream) {
    const float* A = (const float*)d_in[0];
    const float* B = (const float*)d_in[1];
    float* out = (float*)d_out;
    int n = in_sizes[0] / 64;                         // rows
    int nwaves = n / 64;                              // one wave per 64 rows
    int block = 256;
    int grid = (nwaves * 64 + block - 1) / block;
    spike_fp64_mul_kernel<<<grid, block, 0, stream>>>(A, B, out, n);
}

// Round 3
// 20.261 us; speedup vs baseline: 2.6485x; 1.1901x over previous
//
#include <hip/hip_runtime.h>

typedef unsigned long long u64;

// Exact integer re-implementation of the reference "spiking" fp64-multiplier
// circuit. Bit convention: array index j (0..63) of a row == bit (63-j) of
// the packed uint64 (sign at array[0] == bit 63).
__device__ __forceinline__ u64 fp64mul_circuit(u64 a, u64 b) {
    const u64 FRACM = 0xFFFFFFFFFFFFFULL; // low 52 bits
    u64 sA = a >> 63, sB = b >> 63;
    unsigned eA = (unsigned)((a >> 52) & 0x7FF);
    unsigned eB = (unsigned)((b >> 52) & 0x7FF);
    u64 mA = a & FRACM, mB = b & FRACM;
    u64 sign = sA ^ sB;

    u64 MA = mA | ((u64)(eA != 0) << 52);
    u64 MB = mB | ((u64)(eB != 0) << 52);
    __uint128_t P = (__uint128_t)MA * (__uint128_t)MB; // < 2^106, in 108-bit field

    u64 hi = (u64)(P >> 64), lo = (u64)P;
    int lzc;
    if (hi)      lzc = __clzll(hi) - 20;      // bits 107..64 live in hi[43:0]
    else if (lo) lzc = 44 + __clzll(lo);
    else         lzc = 108;

    __uint128_t norm = P << lzc;              // leading one -> bit 107 (P==0 -> 0)

    u64 mant53     = (u64)(norm >> 55);                  // bits 107..55
    unsigned guard = (unsigned)(((u64)(norm >> 54)) & 1);
    unsigned lsb   = (unsigned)(mant53 & 1);
    unsigned sticky = ((norm & ((((__uint128_t)1) << 54) - 1)) != 0) ? 1u : 0u;
    unsigned rnd   = guard & (sticky | lsb);             // round to nearest even

    u64 sum = mant53 + (u64)rnd;
    unsigned rcarry = (unsigned)((sum >> 53) & 1);
    u64 frac52 = sum & FRACM;

    int Emod = ((int)eA + (int)eB + 3 - 1023 - lzc + (int)rcarry) & 8191;
    int neg    = (Emod >> 12) & 1;
    int e_zero = (Emod == 0) ? 1 : 0;
    int underflow = neg | e_zero;
    int overflow  = (neg ^ 1) & ((((Emod >> 11) & 1) | ((Emod & 0x7FF) == 0x7FF)) ? 1 : 0);
    u64 exp11 = (u64)(Emod & 0x7FF);

    bool a_ones = (eA == 0x7FF), b_ones = (eB == 0x7FF);
    bool a_mnz = (mA != 0), b_mnz = (mB != 0);
    bool A_nan = a_ones && a_mnz,  B_nan = b_ones && b_mnz;
    bool A_inf = a_ones && !a_mnz, B_inf = b_ones && !b_mnz;
    bool A_zero = (eA == 0) && !a_mnz, B_zero = (eB == 0) && !b_mnz;

    bool nan_sel  = A_nan || B_nan || (A_inf && B_zero) || (B_inf && A_zero);
    bool inf_sel  = A_inf || B_inf || (overflow != 0);
    bool zero_sel = A_zero || B_zero || (underflow != 0);

    u64 expo = exp11, fraco = frac52;
    if (zero_sel) { expo = 0;     fraco = 0; }
    if (inf_sel)  { expo = 0x7FF; fraco = 0; }
    if (nan_sel)  { expo = 0x7FF; fraco = 1ULL << 51; } // qnan: frac MSB only

    return (sign << 63) | (expo << 52) | fraco;
}

// One wave handles ROWS rows. Lane l is bit-column l for loads/stores
// (64 lanes x 4B = 256B contiguous per memory instruction). All loads are
// prefetched into registers BEFORE the first ballot so the 2*ROWS loads
// overlap (memory latency paid once). Lane r keeps row r's packed bits.
#define ROWS 16

__global__ __launch_bounds__(256) void spike_fp64_mul_kernel(
    const float* __restrict__ A, const float* __restrict__ B,
    float* __restrict__ out, int n)
{
    int gtid = blockIdx.x * blockDim.x + threadIdx.x;
    int wave = gtid >> 6;
    int lane = threadIdx.x & 63;
    int nwaves = n / ROWS;
    if (wave >= nwaves) return;

    size_t rowbase = (size_t)wave * ROWS;
    const float* pa = A + rowbase * 64 + lane;
    const float* pb = B + rowbase * 64 + lane;

    // Prefetch: 2*ROWS independent coalesced loads in flight at once.
    float va[ROWS], vb[ROWS];
    #pragma unroll
    for (int r = 0; r < ROWS; ++r) {
        va[r] = pa[(size_t)r * 64];
        vb[r] = pb[(size_t)r * 64];
    }

    // Pack: one ballot per row (bit l = array index l); route row r to lane r.
    u64 a = 0, b = 0;
    #pragma unroll
    for (int r = 0; r < ROWS; ++r) {
        u64 balA = __ballot(va[r] > 0.5f);
        u64 balB = __ballot(vb[r] > 0.5f);
        if (lane == r) { a = balA; b = balB; }
    }

    // All lanes compute (lanes >= ROWS produce junk that is never stored).
    u64 res = fp64mul_circuit(__brevll(a), __brevll(b));

    float* po = out + rowbase * 64 + lane;
    #pragma unroll
    for (int r = 0; r < ROWS; ++r) {
        u64 v = __shfl(res, r);                      // row base+r -> all lanes
        po[(size_t)r * 64] = (float)((v >> (63 - lane)) & 1);
    }
}

extern "C" void kernel_launch(void* const* d_in, const int* in_sizes, int n_in,
                              void* d_out, int out_size, void* d_ws, size_t ws_size,
                              hipStream_t stream) {
    const float* A = (const float*)d_in[0];
    const float* B = (const float*)d_in[1];
    float* out = (float*)d_out;
    int n = in_sizes[0] / 64;                        // rows
    int nwaves = n / ROWS;
    int block = 256;
    int grid = (nwaves * 64 + block - 1) / block;
    spike_fp64_mul_kernel<<<grid, block, 0, stream>>>(A, B, out, n);
}

// Round 4
// 19.923 us; speedup vs baseline: 2.6934x; 1.0170x over previous
//
#include <hip/hip_runtime.h>

typedef unsigned long long u64;

// Exact integer re-implementation of the reference "spiking" fp64-multiplier
// circuit. Bit convention: array index j (0..63) of a row == bit (63-j) of
// the packed uint64 (sign at array[0] == bit 63).
__device__ __forceinline__ u64 fp64mul_circuit(u64 a, u64 b) {
    const u64 FRACM = 0xFFFFFFFFFFFFFULL; // low 52 bits
    u64 sA = a >> 63, sB = b >> 63;
    unsigned eA = (unsigned)((a >> 52) & 0x7FF);
    unsigned eB = (unsigned)((b >> 52) & 0x7FF);
    u64 mA = a & FRACM, mB = b & FRACM;
    u64 sign = sA ^ sB;

    u64 MA = mA | ((u64)(eA != 0) << 52);
    u64 MB = mB | ((u64)(eB != 0) << 52);
    __uint128_t P = (__uint128_t)MA * (__uint128_t)MB; // < 2^106, in 108-bit field

    u64 hi = (u64)(P >> 64), lo = (u64)P;
    int lzc;
    if (hi)      lzc = __clzll(hi) - 20;      // bits 107..64 live in hi[43:0]
    else if (lo) lzc = 44 + __clzll(lo);
    else         lzc = 108;

    __uint128_t norm = P << lzc;              // leading one -> bit 107 (P==0 -> 0)

    u64 mant53     = (u64)(norm >> 55);                  // bits 107..55
    unsigned guard = (unsigned)(((u64)(norm >> 54)) & 1);
    unsigned lsb   = (unsigned)(mant53 & 1);
    unsigned sticky = ((norm & ((((__uint128_t)1) << 54) - 1)) != 0) ? 1u : 0u;
    unsigned rnd   = guard & (sticky | lsb);             // round to nearest even

    u64 sum = mant53 + (u64)rnd;
    unsigned rcarry = (unsigned)((sum >> 53) & 1);
    u64 frac52 = sum & FRACM;

    int Emod = ((int)eA + (int)eB + 3 - 1023 - lzc + (int)rcarry) & 8191;
    int neg    = (Emod >> 12) & 1;
    int e_zero = (Emod == 0) ? 1 : 0;
    int underflow = neg | e_zero;
    int overflow  = (neg ^ 1) & ((((Emod >> 11) & 1) | ((Emod & 0x7FF) == 0x7FF)) ? 1 : 0);
    u64 exp11 = (u64)(Emod & 0x7FF);

    bool a_ones = (eA == 0x7FF), b_ones = (eB == 0x7FF);
    bool a_mnz = (mA != 0), b_mnz = (mB != 0);
    bool A_nan = a_ones && a_mnz,  B_nan = b_ones && b_mnz;
    bool A_inf = a_ones && !a_mnz, B_inf = b_ones && !b_mnz;
    bool A_zero = (eA == 0) && !a_mnz, B_zero = (eB == 0) && !b_mnz;

    bool nan_sel  = A_nan || B_nan || (A_inf && B_zero) || (B_inf && A_zero);
    bool inf_sel  = A_inf || B_inf || (overflow != 0);
    bool zero_sel = A_zero || B_zero || (underflow != 0);

    u64 expo = exp11, fraco = frac52;
    if (zero_sel) { expo = 0;     fraco = 0; }
    if (inf_sel)  { expo = 0x7FF; fraco = 0; }
    if (nan_sel)  { expo = 0x7FF; fraco = 1ULL << 51; } // qnan: frac MSB only

    return (sign << 63) | (expo << 52) | fraco;
}

#define ROWS 16   // rows per wave
#define WPB  4    // waves per block (256 threads)

// All global memory moves as dwordx4 (16B/lane, 1KB/instruction):
//   8 x 1KB loads + 4 x 1KB stores per wave of 16 rows (vs 48 x 256B before).
// A small LDS transpose bridges the row-major float layout and the per-lane
// packed-u64 circuit: float4 -> 4-bit nibble -> LDS byte -> per-row b128 read
// -> byte->nibble compaction -> u64.
__global__ __launch_bounds__(256) void spike_fp64_mul_kernel(
    const float* __restrict__ A, const float* __restrict__ B,
    float* __restrict__ out, int n)
{
    __shared__ alignas(16) unsigned char nibA[WPB][ROWS][16];
    __shared__ alignas(16) unsigned char nibB[WPB][ROWS][16];
    __shared__ u64 resLds[WPB][ROWS];

    int lane = threadIdx.x & 63;
    int wib  = threadIdx.x >> 6;
    int wave = (blockIdx.x * blockDim.x + threadIdx.x) >> 6;
    int k = lane >> 4;   // row sub-index within a 4-row load instruction
    int m = lane & 15;   // float4 (nibble) slot within a row

    size_t rowbase = (size_t)wave * ROWS;
    const float4* A4 = reinterpret_cast<const float4*>(A);
    const float4* B4 = reinterpret_cast<const float4*>(B);

    // Prefetch all 8 x 1KB loads, then pack. Each float4 becomes a nibble
    // (bit c = col 4m+c of its row).
    float4 ra[4], rb[4];
    #pragma unroll
    for (int j = 0; j < 4; ++j) {
        int row = 4 * j + k;
        ra[j] = A4[(rowbase + row) * 16 + m];
        rb[j] = B4[(rowbase + row) * 16 + m];
    }
    #pragma unroll
    for (int j = 0; j < 4; ++j) {
        int row = 4 * j + k;
        unsigned na = (unsigned)(ra[j].x > 0.5f)       | ((unsigned)(ra[j].y > 0.5f) << 1)
                    | ((unsigned)(ra[j].z > 0.5f) << 2) | ((unsigned)(ra[j].w > 0.5f) << 3);
        unsigned nb = (unsigned)(rb[j].x > 0.5f)       | ((unsigned)(rb[j].y > 0.5f) << 1)
                    | ((unsigned)(rb[j].z > 0.5f) << 2) | ((unsigned)(rb[j].w > 0.5f) << 3);
        nibA[wib][row][m] = (unsigned char)na;
        nibB[wib][row][m] = (unsigned char)nb;
    }
    __syncthreads();

    // Each lane reconstructs row (lane&15) as a packed u64 (bit idx = col).
    // Lanes 16..63 duplicate lanes 0..15 (same LDS addr -> broadcast, no
    // divergence; redundant compute is free at 5% VALU).
    int rr = m;
    uint4 wa = *reinterpret_cast<const uint4*>(nibA[wib][rr]);
    uint4 wb = *reinterpret_cast<const uint4*>(nibB[wib][rr]);
    u64 rowA = 0, rowB = 0;
    {
        unsigned va_[4] = {wa.x, wa.y, wa.z, wa.w};
        unsigned vb_[4] = {wb.x, wb.y, wb.z, wb.w};
        #pragma unroll
        for (int q = 0; q < 4; ++q) {
            unsigned v = va_[q] & 0x0F0F0F0Fu;          // byte t holds nibble 4q+t
            v = (v | (v >> 4)) & 0x00FF00FFu;
            v = (v | (v >> 8)) & 0x0000FFFFu;           // 16 bits: bit 4t+c
            rowA |= (u64)v << (16 * q);
            unsigned w = vb_[q] & 0x0F0F0F0Fu;
            w = (w | (w >> 4)) & 0x00FF00FFu;
            w = (w | (w >> 8)) & 0x0000FFFFu;
            rowB |= (u64)w << (16 * q);
        }
    }

    // Circuit wants MSB-first packing (bit 63-idx).
    u64 res = fp64mul_circuit(__brevll(rowA), __brevll(rowB));

    if (lane < ROWS) resLds[wib][lane] = res;
    __syncthreads();

    // 4 x 1KB coalesced stores: inst i covers rows 4i..4i+3.
    float4* O4 = reinterpret_cast<float4*>(out);
    #pragma unroll
    for (int i = 0; i < 4; ++i) {
        int row = 4 * i + k;
        u64 v = resLds[wib][row];                       // 16-lane broadcast reads
        unsigned nib = (unsigned)(v >> (60 - 4 * m)) & 0xFu; // bits of cols 4m..4m+3
        float4 o;
        o.x = (float)((nib >> 3) & 1);
        o.y = (float)((nib >> 2) & 1);
        o.z = (float)((nib >> 1) & 1);
        o.w = (float)(nib & 1);
        O4[(rowbase + row) * 16 + m] = o;
    }
}

extern "C" void kernel_launch(void* const* d_in, const int* in_sizes, int n_in,
                              void* d_out, int out_size, void* d_ws, size_t ws_size,
                              hipStream_t stream) {
    const float* A = (const float*)d_in[0];
    const float* B = (const float*)d_in[1];
    float* out = (float*)d_out;
    int n = in_sizes[0] / 64;            // rows (131072; multiple of 64)
    int block = 256;                     // 4 waves x 16 rows = 64 rows/block
    int grid = n / 64;
    spike_fp64_mul_kernel<<<grid, block, 0, stream>>>(A, B, out, n);
}